// Round 15
// baseline (250.467 us; speedup 1.0000x reference)
//
#include <hip/hip_runtime.h>
#include <math.h>

namespace {

constexpr int       kNME    = 262144;
constexpr int       kNDOF   = 524288;
constexpr long long kNNZ    = 16777216;   // kNME * 64
constexpr int       kNB     = 64;         // buckets
constexpr int       kBShift = 13;         // 8192 dofs / bucket
constexpr int       kBSpan  = 8192;
constexpr int       kEnt    = 8192;       // entries per producer block
constexpr int       kPTh   = 1024;        // producer threads
constexpr int       kPerTh  = 8;          // kEnt / kPTh
constexpr int       kCtrStride = 16;      // counters padded to 64 B

constexpr float kEmin    = 1e-9f;
constexpr float kEmax    = 1.0f;
constexpr float kVolfrac = 0.4f;

using u32   = unsigned;
using i32x4 = __attribute__((ext_vector_type(4))) int;
using f32x4 = __attribute__((ext_vector_type(4))) float;
using u32x4 = __attribute__((ext_vector_type(4))) unsigned;

// pair = (localrow:13 bits << 19) | (fp32 bits >> 13)  [sign+exp+10 mantissa]
__device__ __forceinline__ u32 pack32(unsigned localrow, float v) {
    return (localrow << 19) | (__float_as_uint(v) >> 13);
}

// ---------------------------------------------------------------------------
// Kernel 1: per-element SIMP scale + rho partial sum.
// ---------------------------------------------------------------------------
__global__ void scale_kernel(const float* __restrict__ W_x,
                             float* __restrict__ scale,
                             float* __restrict__ rho_sum) {
    int i = blockIdx.x * blockDim.x + threadIdx.x;
    float rho = 0.0f;
    if (i < kNME) {
        float x = W_x[i];
        rho = 1.0f / (1.0f + __expf(-x));
        scale[i] = kEmin + rho * rho * rho * (kEmax - kEmin);
    }
    for (int off = 32; off > 0; off >>= 1) rho += __shfl_down(rho, off, 64);
    __shared__ float partial[4];
    const int lane = threadIdx.x & 63;
    const int wid  = threadIdx.x >> 6;
    if (lane == 0) partial[wid] = rho;
    __syncthreads();
    if (threadIdx.x == 0)
        atomicAdd(rho_sum, partial[0] + partial[1] + partial[2] + partial[3]);
}

// ---------------------------------------------------------------------------
// Producer: 1024 threads x 8 entries = 8192/block.
// nt loads ONLY on the once-through input streams (rows/cols/K_sep) so they
// don't thrash L2; pairs stores are CACHED so the consumer hits L2/L3.
// rv[j]: bits[0:18] = row (19b), bits[19:31] = rank (13b, max 8191).
// ---------------------------------------------------------------------------
__global__ __launch_bounds__(kPTh, 8)
void producer_kernel(const float* __restrict__ K_sep,
                     const int*   __restrict__ rows,
                     const int*   __restrict__ cols,
                     const float* __restrict__ u,
                     const float* __restrict__ scale,
                     u32*         __restrict__ pairs,
                     unsigned*    __restrict__ counters,  // [kNB*R*kCtrStride]
                     unsigned capSub, int R) {
    __shared__ unsigned hist[kNB], ofs[kNB], gbase[kNB];
    __shared__ u32      sorted[kEnt];     // 32 KB

    const int tid = threadIdx.x;
    const int sub = blockIdx.x & (R - 1);
    if (tid < kNB) hist[tid] = 0u;
    __syncthreads();

    const long long i0 =
        (long long)blockIdx.x * kEnt + (long long)tid * kPerTh;
    i32x4 r0 = __builtin_nontemporal_load((const i32x4*)(rows + i0));
    i32x4 r1 = __builtin_nontemporal_load((const i32x4*)(rows + i0) + 1);
    i32x4 c0 = __builtin_nontemporal_load((const i32x4*)(cols + i0));
    i32x4 c1 = __builtin_nontemporal_load((const i32x4*)(cols + i0) + 1);
    f32x4 k0 = __builtin_nontemporal_load((const f32x4*)(K_sep + i0));
    f32x4 k1 = __builtin_nontemporal_load((const f32x4*)(K_sep + i0) + 1);
    const float s = scale[(int)(i0 >> 6)];   // all 8 share one element

    unsigned rv[kPerTh];
    float    vv[kPerTh];
#pragma unroll
    for (int j = 0; j < 4; ++j) {
        rv[j]     = (unsigned)r0[j];  vv[j]     = k0[j] * s * u[c0[j]];
        rv[j + 4] = (unsigned)r1[j];  vv[j + 4] = k1[j] * s * u[c1[j]];
    }
    // Histogram; the returned old value IS this entry's rank in its bucket.
#pragma unroll
    for (int j = 0; j < kPerTh; ++j)
        rv[j] |= atomicAdd(&hist[rv[j] >> kBShift], 1u) << 19;
    __syncthreads();

    // Threads 0..63: exclusive scan over buckets + reserve global sub-ranges.
    if (tid < kNB) {
        unsigned h = hist[tid];
        unsigned x = h;
#pragma unroll
        for (int off = 1; off < kNB; off <<= 1) {
            unsigned y = __shfl_up(x, off, 64);
            if (tid >= off) x += y;
        }
        ofs[tid]   = x - h;
        gbase[tid] = atomicAdd(&counters[(tid * R + sub) * kCtrStride], h);
    }
    __syncthreads();

    // Scatter into sorted LDS order — no atomics (rank precomputed).
#pragma unroll
    for (int j = 0; j < kPerTh; ++j) {
        unsigned row = rv[j] & 0x7FFFFu;
        unsigned b   = row >> kBShift;
        unsigned pos = ofs[b] + (rv[j] >> 19);
        sorted[pos]  = pack32(row & (kBSpan - 1), vv[j]);
    }
    __syncthreads();

    // Coalesced copy-out: 16 waves, 4 bucket runs each (~128 entries/run).
    // CACHED stores: pairs stay in L2/L3 for the consumer.
    const int wid = tid >> 6, lane = tid & 63;
    for (int b = wid; b < kNB; b += 16) {
        const unsigned s0 = ofs[b];
        const unsigned n  = hist[b];
        const unsigned g  = gbase[b];
        u32* dst = pairs + (size_t)(b * R + sub) * capSub + g;
        for (unsigned i = lane; i < n; i += 64) {
            if (g + i < capSub) dst[i] = sorted[s0 + i];
        }
    }
}

// ---------------------------------------------------------------------------
// Consumer: block (b, sub) owns one sub-region. 512 threads, cached u32x4
// loads (pairs are L2/L3-hot), LDS atomics, private plane store.
// ---------------------------------------------------------------------------
__global__ __launch_bounds__(512, 8)
void consumer_kernel(const u32*      __restrict__ pairs,
                     const unsigned* __restrict__ counters,
                     float*          __restrict__ partial,
                     unsigned capSub, int R) {
    const int b   = blockIdx.x / R;
    const int sub = blockIdx.x - b * R;
    unsigned cnt = counters[(b * R + sub) * kCtrStride];
    if (cnt > capSub) cnt = capSub;

    __shared__ float acc[kBSpan];
    for (int i = threadIdx.x; i < kBSpan; i += 512) acc[i] = 0.0f;
    __syncthreads();

    const u32* p = pairs + (size_t)(b * R + sub) * capSub;
    const unsigned aligned = cnt & ~3u;
    for (unsigned i = 4 * threadIdx.x; i < aligned; i += 2048) {
        u32x4 e = *((const u32x4*)(p + i));
#pragma unroll
        for (int j = 0; j < 4; ++j)
            atomicAdd(&acc[e[j] >> 19], __uint_as_float(e[j] << 13));
    }
    if (threadIdx.x < (cnt - aligned)) {
        u32 e = p[aligned + threadIdx.x];
        atomicAdd(&acc[e >> 19], __uint_as_float(e << 13));
    }
    __syncthreads();

    float* dst = partial + (size_t)(b * R + sub) * kBSpan;
    for (int k = threadIdx.x; k < kBSpan; k += 512) dst[k] = acc[k];
}

// ---------------------------------------------------------------------------
// Norm + finalize: block (b, chunk of 1024 dofs); vectorized sum over R
// planes; done-counter finalize (thread 0 only).
// acc layout: acc[0]=rho_sum, acc[1]=norm_sum, acc[2]=done counter (uint).
// ---------------------------------------------------------------------------
__global__ void norm_kernel(const float* __restrict__ partial,
                            const float* __restrict__ f,
                            float* __restrict__ acc,
                            float* __restrict__ out, int R) {
    const int b  = blockIdx.x >> 3;
    const int i0 = (blockIdx.x & 7) * 1024 + threadIdx.x * 4;
    f32x4 s = {0.0f, 0.0f, 0.0f, 0.0f};
    for (int r = 0; r < R; ++r)
        s += *(const f32x4*)(partial + (size_t)(b * R + r) * kBSpan + i0);
    f32x4 fv = *(const f32x4*)(f + (size_t)b * kBSpan + i0);
    f32x4 d  = s - fv;
    float a = d[0] * d[0] + d[1] * d[1] + d[2] * d[2] + d[3] * d[3];
    for (int off = 32; off > 0; off >>= 1) a += __shfl_down(a, off, 64);
    __shared__ float partial_s[4];
    const int lane = threadIdx.x & 63;
    const int wid  = threadIdx.x >> 6;
    if (lane == 0) partial_s[wid] = a;
    __syncthreads();
    if (threadIdx.x == 0) {
        atomicAdd(&acc[1],
                  partial_s[0] + partial_s[1] + partial_s[2] + partial_s[3]);
        __threadfence();
        unsigned done = atomicAdd((unsigned*)&acc[2], 1u);
        if (done == gridDim.x - 1) {
            float rs = __hip_atomic_load(&acc[0], __ATOMIC_RELAXED,
                                         __HIP_MEMORY_SCOPE_AGENT);
            float ns = __hip_atomic_load(&acc[1], __ATOMIC_RELAXED,
                                         __HIP_MEMORY_SCOPE_AGENT);
            float rho_mean = rs * (1.0f / (float)kNME);
            out[0] = fmaxf(rho_mean - kVolfrac, 0.0f) + sqrtf(ns);
        }
    }
}

// ---------------------------------------------------------------------------
// Fallback path (device atomics) if workspace is too small.
// ---------------------------------------------------------------------------
__global__ void scatter_dev_kernel(const float* __restrict__ K_sep,
                                   const int*   __restrict__ rows,
                                   const int*   __restrict__ cols,
                                   const float* __restrict__ u,
                                   const float* __restrict__ scale,
                                   float* __restrict__ Ku) {
    long long i = (long long)blockIdx.x * blockDim.x + threadIdx.x;
    if (i >= kNNZ) return;
    float s = scale[(int)(i >> 6)];
    atomicAdd(&Ku[rows[i]], K_sep[i] * s * u[cols[i]]);
}

__global__ void norm1_kernel(const float* __restrict__ Ku,
                             const float* __restrict__ f,
                             float* __restrict__ norm_sum) {
    float a = 0.0f;
    for (int i = blockIdx.x * blockDim.x + threadIdx.x; i < kNDOF;
         i += gridDim.x * blockDim.x) {
        float d = Ku[i] - f[i];
        a += d * d;
    }
    for (int off = 32; off > 0; off >>= 1) a += __shfl_down(a, off, 64);
    __shared__ float partial_s[4];
    const int lane = threadIdx.x & 63;
    const int wid  = threadIdx.x >> 6;
    if (lane == 0) partial_s[wid] = a;
    __syncthreads();
    if (threadIdx.x == 0)
        atomicAdd(norm_sum,
                  partial_s[0] + partial_s[1] + partial_s[2] + partial_s[3]);
}

__global__ void finalize_kernel(const float* __restrict__ acc,
                                float* __restrict__ out) {
    if (threadIdx.x == 0 && blockIdx.x == 0) {
        float rho_mean = acc[0] * (1.0f / (float)kNME);
        float vol = fmaxf(rho_mean - kVolfrac, 0.0f);
        out[0] = vol + sqrtf(acc[1]);
    }
}

}  // namespace

extern "C" void kernel_launch(void* const* d_in, const int* in_sizes, int n_in,
                              void* d_out, int out_size, void* d_ws, size_t ws_size,
                              hipStream_t stream) {
    const float* W_x   = (const float*)d_in[0];
    const float* K_sep = (const float*)d_in[1];
    const int*   idx   = (const int*)d_in[2];
    const float* u     = (const float*)d_in[3];
    const float* f     = (const float*)d_in[4];
    const int* rows = idx;
    const int* cols = idx + kNNZ;

    float* ws = (float*)d_ws;
    const size_t avail = ws_size / sizeof(float);

    // Single-chunk config: R=16 subs, margin 2048.
    const int      R      = 16;
    const unsigned capSub = (unsigned)(kNNZ / (kNB * R)) + 2048;
    const size_t   ctrF   = (size_t)kNB * R * kCtrStride;          // 16384
    const size_t   headF  = 16;                                    // acc
    const size_t   partF  = (size_t)kNB * R * kBSpan;              // 8.4M
    const size_t   need   = headF + ctrF + partF + kNME +
                            (size_t)kNB * R * capSub;

    if (need > avail) {
        // Fallback: device-atomic scatter (fits in ~3.2 MB).
        float* Ku    = ws;
        float* scale = ws + kNDOF;
        float* acc   = ws + kNDOF + kNME;
        hipMemsetAsync(ws, 0, (size_t)(kNDOF + kNME + 16) * sizeof(float), stream);
        scale_kernel<<<kNME / 256, 256, 0, stream>>>(W_x, scale, acc);
        scatter_dev_kernel<<<(int)(kNNZ / 256), 256, 0, stream>>>(
            K_sep, rows, cols, u, scale, Ku);
        norm1_kernel<<<2048, 256, 0, stream>>>(Ku, f, acc + 1);
        finalize_kernel<<<1, 64, 0, stream>>>(acc, (float*)d_out);
        return;
    }

    float*    acc      = ws;                          // [16] rho,norm,done
    unsigned* counters = (unsigned*)(ws + headF);     // [kNB*R*kCtrStride]
    float*    partial  = ws + headF + ctrF;           // [kNB*R*kBSpan]
    float*    scale    = partial + partF;             // [kNME]
    u32*      pairs    = (u32*)(scale + kNME);        // [kNB*R*capSub]

    // Zero acc + counters (replay-safe).
    hipMemsetAsync(ws, 0, (headF + ctrF) * sizeof(float), stream);

    scale_kernel<<<kNME / 256, 256, 0, stream>>>(W_x, scale, acc);

    producer_kernel<<<(int)(kNNZ / kEnt), kPTh, 0, stream>>>(
        K_sep, rows, cols, u, scale, pairs, counters, capSub, R);

    consumer_kernel<<<kNB * R, 512, 0, stream>>>(
        pairs, counters, partial, capSub, R);

    norm_kernel<<<kNB * (kBSpan / 1024), 256, 0, stream>>>(
        partial, f, acc, (float*)d_out, R);
}

// Round 16
// 243.031 us; speedup vs baseline: 1.0306x; 1.0306x over previous
//
#include <hip/hip_runtime.h>
#include <math.h>

namespace {

constexpr int       kNME    = 262144;
constexpr int       kNDOF   = 524288;
constexpr long long kNNZ    = 16777216;   // kNME * 64
constexpr int       kNB     = 64;         // buckets
constexpr int       kBShift = 13;         // 8192 dofs / bucket
constexpr int       kBSpan  = 8192;
constexpr int       kEnt    = 8192;       // entries per producer block
constexpr int       kPTh   = 1024;        // producer threads
constexpr int       kPerTh  = 8;          // kEnt / kPTh
constexpr int       kCtrStride = 16;      // counters padded to 64 B
constexpr int       kScaleBlocks = kNME / 256;   // 1024

constexpr float kEmin    = 1e-9f;
constexpr float kEmax    = 1.0f;
constexpr float kVolfrac = 0.4f;

using u32   = unsigned;
using i32x4 = __attribute__((ext_vector_type(4))) int;
using f32x4 = __attribute__((ext_vector_type(4))) float;
using u32x4 = __attribute__((ext_vector_type(4))) unsigned;

// pair = (localrow:13 bits << 19) | (fp32 bits >> 13)  [sign+exp+10 mantissa]
__device__ __forceinline__ u32 pack32(unsigned localrow, float v) {
    return (localrow << 19) | (__float_as_uint(v) >> 13);
}

// ---------------------------------------------------------------------------
// Kernel 1: SIMP scale + workspace init (replaces the memset node).
//  - zeroes acc[1..15] and the counters (16K words over 262K threads)
//  - writes per-block rho partials (plain stores, no zeroing needed)
// ---------------------------------------------------------------------------
__global__ void scale_kernel(const float* __restrict__ W_x,
                             float* __restrict__ scale,
                             float* __restrict__ acc,       // [16]
                             unsigned* __restrict__ counters,
                             float* __restrict__ rho_part) { // [kScaleBlocks]
    const int gid = blockIdx.x * blockDim.x + threadIdx.x;

    // Init duties (race-free: nothing else writes these until later kernels).
    if (gid >= 1 && gid < 16) acc[gid] = 0.0f;
    const int cidx = gid - 16;
    if (cidx >= 0 && cidx < kNB * 16 * kCtrStride) counters[cidx] = 0u;

    float rho = 0.0f;
    if (gid < kNME) {
        float x = W_x[gid];
        rho = 1.0f / (1.0f + __expf(-x));
        scale[gid] = kEmin + rho * rho * rho * (kEmax - kEmin);
    }
    for (int off = 32; off > 0; off >>= 1) rho += __shfl_down(rho, off, 64);
    __shared__ float partial[4];
    const int lane = threadIdx.x & 63;
    const int wid  = threadIdx.x >> 6;
    if (lane == 0) partial[wid] = rho;
    __syncthreads();
    if (threadIdx.x == 0)
        rho_part[blockIdx.x] =
            partial[0] + partial[1] + partial[2] + partial[3];
}

// ---------------------------------------------------------------------------
// Producer (round-15 exact): 1024 threads x 8 entries = 8192/block.
// nt loads on the once-through input streams; cached pair stores.
// rv[j]: bits[0:18] = row (19b), bits[19:31] = rank (13b, max 8191).
// ---------------------------------------------------------------------------
__global__ __launch_bounds__(kPTh, 8)
void producer_kernel(const float* __restrict__ K_sep,
                     const int*   __restrict__ rows,
                     const int*   __restrict__ cols,
                     const float* __restrict__ u,
                     const float* __restrict__ scale,
                     u32*         __restrict__ pairs,
                     unsigned*    __restrict__ counters,  // [kNB*R*kCtrStride]
                     unsigned capSub, int R) {
    __shared__ unsigned hist[kNB], ofs[kNB], gbase[kNB];
    __shared__ u32      sorted[kEnt];     // 32 KB

    const int tid = threadIdx.x;
    const int sub = blockIdx.x & (R - 1);
    if (tid < kNB) hist[tid] = 0u;
    __syncthreads();

    const long long i0 =
        (long long)blockIdx.x * kEnt + (long long)tid * kPerTh;
    i32x4 r0 = __builtin_nontemporal_load((const i32x4*)(rows + i0));
    i32x4 r1 = __builtin_nontemporal_load((const i32x4*)(rows + i0) + 1);
    i32x4 c0 = __builtin_nontemporal_load((const i32x4*)(cols + i0));
    i32x4 c1 = __builtin_nontemporal_load((const i32x4*)(cols + i0) + 1);
    f32x4 k0 = __builtin_nontemporal_load((const f32x4*)(K_sep + i0));
    f32x4 k1 = __builtin_nontemporal_load((const f32x4*)(K_sep + i0) + 1);
    const float s = scale[(int)(i0 >> 6)];   // all 8 share one element

    unsigned rv[kPerTh];
    float    vv[kPerTh];
#pragma unroll
    for (int j = 0; j < 4; ++j) {
        rv[j]     = (unsigned)r0[j];  vv[j]     = k0[j] * s * u[c0[j]];
        rv[j + 4] = (unsigned)r1[j];  vv[j + 4] = k1[j] * s * u[c1[j]];
    }
    // Histogram; the returned old value IS this entry's rank in its bucket.
#pragma unroll
    for (int j = 0; j < kPerTh; ++j)
        rv[j] |= atomicAdd(&hist[rv[j] >> kBShift], 1u) << 19;
    __syncthreads();

    // Threads 0..63: exclusive scan over buckets + reserve global sub-ranges.
    if (tid < kNB) {
        unsigned h = hist[tid];
        unsigned x = h;
#pragma unroll
        for (int off = 1; off < kNB; off <<= 1) {
            unsigned y = __shfl_up(x, off, 64);
            if (tid >= off) x += y;
        }
        ofs[tid]   = x - h;
        gbase[tid] = atomicAdd(&counters[(tid * R + sub) * kCtrStride], h);
    }
    __syncthreads();

    // Scatter into sorted LDS order — no atomics (rank precomputed).
#pragma unroll
    for (int j = 0; j < kPerTh; ++j) {
        unsigned row = rv[j] & 0x7FFFFu;
        unsigned b   = row >> kBShift;
        unsigned pos = ofs[b] + (rv[j] >> 19);
        sorted[pos]  = pack32(row & (kBSpan - 1), vv[j]);
    }
    __syncthreads();

    // Coalesced copy-out: 16 waves, 4 bucket runs each (~128 entries/run).
    const int wid = tid >> 6, lane = tid & 63;
    for (int b = wid; b < kNB; b += 16) {
        const unsigned s0 = ofs[b];
        const unsigned n  = hist[b];
        const unsigned g  = gbase[b];
        u32* dst = pairs + (size_t)(b * R + sub) * capSub + g;
        for (unsigned i = lane; i < n; i += 64) {
            if (g + i < capSub) dst[i] = sorted[s0 + i];
        }
    }
}

// ---------------------------------------------------------------------------
// Consumer (round-15 exact): block (b, sub) owns one sub-region.
// ---------------------------------------------------------------------------
__global__ __launch_bounds__(512, 8)
void consumer_kernel(const u32*      __restrict__ pairs,
                     const unsigned* __restrict__ counters,
                     float*          __restrict__ partial,
                     unsigned capSub, int R) {
    const int b   = blockIdx.x / R;
    const int sub = blockIdx.x - b * R;
    unsigned cnt = counters[(b * R + sub) * kCtrStride];
    if (cnt > capSub) cnt = capSub;

    __shared__ float acc[kBSpan];
    for (int i = threadIdx.x; i < kBSpan; i += 512) acc[i] = 0.0f;
    __syncthreads();

    const u32* p = pairs + (size_t)(b * R + sub) * capSub;
    const unsigned aligned = cnt & ~3u;
    for (unsigned i = 4 * threadIdx.x; i < aligned; i += 2048) {
        u32x4 e = *((const u32x4*)(p + i));
#pragma unroll
        for (int j = 0; j < 4; ++j)
            atomicAdd(&acc[e[j] >> 19], __uint_as_float(e[j] << 13));
    }
    if (threadIdx.x < (cnt - aligned)) {
        u32 e = p[aligned + threadIdx.x];
        atomicAdd(&acc[e >> 19], __uint_as_float(e << 13));
    }
    __syncthreads();

    float* dst = partial + (size_t)(b * R + sub) * kBSpan;
    for (int k = threadIdx.x; k < kBSpan; k += 512) dst[k] = acc[k];
}

// ---------------------------------------------------------------------------
// Norm + finalize: vectorized sum over R planes; done-counter finalize.
// The finalizer thread also reduces the rho partials (1024 floats, L2-hot).
// acc layout: acc[1]=norm_sum, acc[2]=done counter (uint).
// ---------------------------------------------------------------------------
__global__ void norm_kernel(const float* __restrict__ partial,
                            const float* __restrict__ f,
                            float* __restrict__ acc,
                            const float* __restrict__ rho_part,
                            float* __restrict__ out, int R) {
    const int b  = blockIdx.x >> 3;
    const int i0 = (blockIdx.x & 7) * 1024 + threadIdx.x * 4;
    f32x4 s = {0.0f, 0.0f, 0.0f, 0.0f};
    for (int r = 0; r < R; ++r)
        s += *(const f32x4*)(partial + (size_t)(b * R + r) * kBSpan + i0);
    f32x4 fv = *(const f32x4*)(f + (size_t)b * kBSpan + i0);
    f32x4 d  = s - fv;
    float a = d[0] * d[0] + d[1] * d[1] + d[2] * d[2] + d[3] * d[3];
    for (int off = 32; off > 0; off >>= 1) a += __shfl_down(a, off, 64);
    __shared__ float partial_s[4];
    const int lane = threadIdx.x & 63;
    const int wid  = threadIdx.x >> 6;
    if (lane == 0) partial_s[wid] = a;
    __syncthreads();
    if (threadIdx.x == 0) {
        atomicAdd(&acc[1],
                  partial_s[0] + partial_s[1] + partial_s[2] + partial_s[3]);
        __threadfence();
        unsigned done = atomicAdd((unsigned*)&acc[2], 1u);
        if (done == gridDim.x - 1) {
            float rs = 0.0f;
            for (int i = 0; i < kScaleBlocks; i += 4) {
                f32x4 rp = *(const f32x4*)(rho_part + i);
                rs += rp[0] + rp[1] + rp[2] + rp[3];
            }
            float ns = __hip_atomic_load(&acc[1], __ATOMIC_RELAXED,
                                         __HIP_MEMORY_SCOPE_AGENT);
            float rho_mean = rs * (1.0f / (float)kNME);
            out[0] = fmaxf(rho_mean - kVolfrac, 0.0f) + sqrtf(ns);
        }
    }
}

// ---------------------------------------------------------------------------
// Fallback path (device atomics) if workspace is too small.
// ---------------------------------------------------------------------------
__global__ void scale1_kernel(const float* __restrict__ W_x,
                              float* __restrict__ scale,
                              float* __restrict__ rho_sum) {
    int i = blockIdx.x * blockDim.x + threadIdx.x;
    float rho = 0.0f;
    if (i < kNME) {
        float x = W_x[i];
        rho = 1.0f / (1.0f + __expf(-x));
        scale[i] = kEmin + rho * rho * rho * (kEmax - kEmin);
    }
    for (int off = 32; off > 0; off >>= 1) rho += __shfl_down(rho, off, 64);
    __shared__ float partial[4];
    const int lane = threadIdx.x & 63;
    const int wid  = threadIdx.x >> 6;
    if (lane == 0) partial[wid] = rho;
    __syncthreads();
    if (threadIdx.x == 0)
        atomicAdd(rho_sum, partial[0] + partial[1] + partial[2] + partial[3]);
}

__global__ void scatter_dev_kernel(const float* __restrict__ K_sep,
                                   const int*   __restrict__ rows,
                                   const int*   __restrict__ cols,
                                   const float* __restrict__ u,
                                   const float* __restrict__ scale,
                                   float* __restrict__ Ku) {
    long long i = (long long)blockIdx.x * blockDim.x + threadIdx.x;
    if (i >= kNNZ) return;
    float s = scale[(int)(i >> 6)];
    atomicAdd(&Ku[rows[i]], K_sep[i] * s * u[cols[i]]);
}

__global__ void norm1_kernel(const float* __restrict__ Ku,
                             const float* __restrict__ f,
                             float* __restrict__ norm_sum) {
    float a = 0.0f;
    for (int i = blockIdx.x * blockDim.x + threadIdx.x; i < kNDOF;
         i += gridDim.x * blockDim.x) {
        float d = Ku[i] - f[i];
        a += d * d;
    }
    for (int off = 32; off > 0; off >>= 1) a += __shfl_down(a, off, 64);
    __shared__ float partial_s[4];
    const int lane = threadIdx.x & 63;
    const int wid  = threadIdx.x >> 6;
    if (lane == 0) partial_s[wid] = a;
    __syncthreads();
    if (threadIdx.x == 0)
        atomicAdd(norm_sum,
                  partial_s[0] + partial_s[1] + partial_s[2] + partial_s[3]);
}

__global__ void finalize_kernel(const float* __restrict__ acc,
                                float* __restrict__ out) {
    if (threadIdx.x == 0 && blockIdx.x == 0) {
        float rho_mean = acc[0] * (1.0f / (float)kNME);
        float vol = fmaxf(rho_mean - kVolfrac, 0.0f);
        out[0] = vol + sqrtf(acc[1]);
    }
}

}  // namespace

extern "C" void kernel_launch(void* const* d_in, const int* in_sizes, int n_in,
                              void* d_out, int out_size, void* d_ws, size_t ws_size,
                              hipStream_t stream) {
    const float* W_x   = (const float*)d_in[0];
    const float* K_sep = (const float*)d_in[1];
    const int*   idx   = (const int*)d_in[2];
    const float* u     = (const float*)d_in[3];
    const float* f     = (const float*)d_in[4];
    const int* rows = idx;
    const int* cols = idx + kNNZ;

    float* ws = (float*)d_ws;
    const size_t avail = ws_size / sizeof(float);

    // Single-chunk config: R=16 subs, margin 2048.
    const int      R      = 16;
    const unsigned capSub = (unsigned)(kNNZ / (kNB * R)) + 2048;
    const size_t   ctrF   = (size_t)kNB * R * kCtrStride;          // 16384
    const size_t   headF  = 16;                                    // acc
    const size_t   rhoF   = kScaleBlocks;                          // 1024
    const size_t   partF  = (size_t)kNB * R * kBSpan;              // 8.4M
    const size_t   need   = headF + ctrF + rhoF + partF + kNME +
                            (size_t)kNB * R * capSub;

    if (need > avail) {
        // Fallback: device-atomic scatter (fits in ~3.2 MB).
        float* Ku    = ws;
        float* scale = ws + kNDOF;
        float* acc   = ws + kNDOF + kNME;
        hipMemsetAsync(ws, 0, (size_t)(kNDOF + kNME + 16) * sizeof(float), stream);
        scale1_kernel<<<kNME / 256, 256, 0, stream>>>(W_x, scale, acc);
        scatter_dev_kernel<<<(int)(kNNZ / 256), 256, 0, stream>>>(
            K_sep, rows, cols, u, scale, Ku);
        norm1_kernel<<<2048, 256, 0, stream>>>(Ku, f, acc + 1);
        finalize_kernel<<<1, 64, 0, stream>>>(acc, (float*)d_out);
        return;
    }

    float*    acc      = ws;                          // [16] norm@1, done@2
    unsigned* counters = (unsigned*)(ws + headF);     // [kNB*R*kCtrStride]
    float*    rho_part = ws + headF + ctrF;           // [kScaleBlocks]
    float*    partial  = rho_part + rhoF;             // [kNB*R*kBSpan]
    float*    scale    = partial + partF;             // [kNME]
    u32*      pairs    = (u32*)(scale + kNME);        // [kNB*R*capSub]

    // Node 1: scale + workspace init (memset node eliminated).
    scale_kernel<<<kScaleBlocks, 256, 0, stream>>>(W_x, scale, acc, counters,
                                                   rho_part);

    // Node 2: producer.
    producer_kernel<<<(int)(kNNZ / kEnt), kPTh, 0, stream>>>(
        K_sep, rows, cols, u, scale, pairs, counters, capSub, R);

    // Node 3: consumer.
    consumer_kernel<<<kNB * R, 512, 0, stream>>>(
        pairs, counters, partial, capSub, R);

    // Node 4: norm + finalize (+ rho reduction in the last block).
    norm_kernel<<<kNB * (kBSpan / 1024), 256, 0, stream>>>(
        partial, f, acc, rho_part, (float*)d_out, R);
}

// Round 17
// 241.403 us; speedup vs baseline: 1.0375x; 1.0067x over previous
//
#include <hip/hip_runtime.h>
#include <math.h>

namespace {

constexpr int       kNME    = 262144;
constexpr int       kNDOF   = 524288;
constexpr long long kNNZ    = 16777216;   // kNME * 64
constexpr int       kNB     = 64;         // buckets
constexpr int       kBShift = 13;         // 8192 dofs / bucket
constexpr int       kBSpan  = 8192;
constexpr int       kEnt    = 8192;       // entries per producer block
constexpr int       kPTh   = 1024;        // producer threads
constexpr int       kPerTh  = 8;          // kEnt / kPTh
constexpr int       kCtrStride = 16;      // counters padded to 64 B
constexpr int       kScaleBlocks = kNME / 256;   // 1024
constexpr int       kR      = 8;          // sub-regions per bucket

constexpr float kEmin    = 1e-9f;
constexpr float kEmax    = 1.0f;
constexpr float kVolfrac = 0.4f;

using u32   = unsigned;
using i32x4 = __attribute__((ext_vector_type(4))) int;
using f32x4 = __attribute__((ext_vector_type(4))) float;
using u32x4 = __attribute__((ext_vector_type(4))) unsigned;

// pair = (localrow:13 bits << 19) | (fp32 bits >> 13)  [sign+exp+10 mantissa]
__device__ __forceinline__ u32 pack32(unsigned localrow, float v) {
    return (localrow << 19) | (__float_as_uint(v) >> 13);
}

// ---------------------------------------------------------------------------
// Kernel 1: SIMP scale + workspace init (no memset node).
// ---------------------------------------------------------------------------
__global__ void scale_kernel(const float* __restrict__ W_x,
                             float* __restrict__ scale,
                             float* __restrict__ acc,       // [16]
                             unsigned* __restrict__ counters,
                             float* __restrict__ rho_part) { // [kScaleBlocks]
    const int gid = blockIdx.x * blockDim.x + threadIdx.x;

    if (gid >= 1 && gid < 16) acc[gid] = 0.0f;
    const int cidx = gid - 16;
    if (cidx >= 0 && cidx < kNB * kR * kCtrStride) counters[cidx] = 0u;

    float rho = 0.0f;
    if (gid < kNME) {
        float x = W_x[gid];
        rho = 1.0f / (1.0f + __expf(-x));
        scale[gid] = kEmin + rho * rho * rho * (kEmax - kEmin);
    }
    for (int off = 32; off > 0; off >>= 1) rho += __shfl_down(rho, off, 64);
    __shared__ float partial[4];
    const int lane = threadIdx.x & 63;
    const int wid  = threadIdx.x >> 6;
    if (lane == 0) partial[wid] = rho;
    __syncthreads();
    if (threadIdx.x == 0)
        rho_part[blockIdx.x] =
            partial[0] + partial[1] + partial[2] + partial[3];
}

// ---------------------------------------------------------------------------
// Producer (round-15/16 exact): 1024 threads x 8 entries = 8192/block.
// nt loads on once-through input streams; cached pair stores.
// rv[j]: bits[0:18] = row (19b), bits[19:31] = rank (13b, max 8191).
// ---------------------------------------------------------------------------
__global__ __launch_bounds__(kPTh, 8)
void producer_kernel(const float* __restrict__ K_sep,
                     const int*   __restrict__ rows,
                     const int*   __restrict__ cols,
                     const float* __restrict__ u,
                     const float* __restrict__ scale,
                     u32*         __restrict__ pairs,
                     unsigned*    __restrict__ counters,  // [kNB*kR*kCtrStride]
                     unsigned capSub) {
    __shared__ unsigned hist[kNB], ofs[kNB], gbase[kNB];
    __shared__ u32      sorted[kEnt];     // 32 KB

    const int tid = threadIdx.x;
    const int sub = blockIdx.x & (kR - 1);
    if (tid < kNB) hist[tid] = 0u;
    __syncthreads();

    const long long i0 =
        (long long)blockIdx.x * kEnt + (long long)tid * kPerTh;
    i32x4 r0 = __builtin_nontemporal_load((const i32x4*)(rows + i0));
    i32x4 r1 = __builtin_nontemporal_load((const i32x4*)(rows + i0) + 1);
    i32x4 c0 = __builtin_nontemporal_load((const i32x4*)(cols + i0));
    i32x4 c1 = __builtin_nontemporal_load((const i32x4*)(cols + i0) + 1);
    f32x4 k0 = __builtin_nontemporal_load((const f32x4*)(K_sep + i0));
    f32x4 k1 = __builtin_nontemporal_load((const f32x4*)(K_sep + i0) + 1);
    const float s = scale[(int)(i0 >> 6)];   // all 8 share one element

    unsigned rv[kPerTh];
    float    vv[kPerTh];
#pragma unroll
    for (int j = 0; j < 4; ++j) {
        rv[j]     = (unsigned)r0[j];  vv[j]     = k0[j] * s * u[c0[j]];
        rv[j + 4] = (unsigned)r1[j];  vv[j + 4] = k1[j] * s * u[c1[j]];
    }
    // Histogram; the returned old value IS this entry's rank in its bucket.
#pragma unroll
    for (int j = 0; j < kPerTh; ++j)
        rv[j] |= atomicAdd(&hist[rv[j] >> kBShift], 1u) << 19;
    __syncthreads();

    // Threads 0..63: exclusive scan over buckets + reserve global sub-ranges.
    if (tid < kNB) {
        unsigned h = hist[tid];
        unsigned x = h;
#pragma unroll
        for (int off = 1; off < kNB; off <<= 1) {
            unsigned y = __shfl_up(x, off, 64);
            if (tid >= off) x += y;
        }
        ofs[tid]   = x - h;
        gbase[tid] = atomicAdd(&counters[(tid * kR + sub) * kCtrStride], h);
    }
    __syncthreads();

    // Scatter into sorted LDS order — no atomics (rank precomputed).
#pragma unroll
    for (int j = 0; j < kPerTh; ++j) {
        unsigned row = rv[j] & 0x7FFFFu;
        unsigned b   = row >> kBShift;
        unsigned pos = ofs[b] + (rv[j] >> 19);
        sorted[pos]  = pack32(row & (kBSpan - 1), vv[j]);
    }
    __syncthreads();

    // Coalesced copy-out: 16 waves, 4 bucket runs each (~128 entries/run).
    const int wid = tid >> 6, lane = tid & 63;
    for (int b = wid; b < kNB; b += 16) {
        const unsigned s0 = ofs[b];
        const unsigned n  = hist[b];
        const unsigned g  = gbase[b];
        u32* dst = pairs + (size_t)(b * kR + sub) * capSub + g;
        for (unsigned i = lane; i < n; i += 64) {
            if (g + i < capSub) dst[i] = sorted[s0 + i];
        }
    }
}

// ---------------------------------------------------------------------------
// Consumer: R=8 -> 512 blocks x 1024 threads (2 blocks/CU = 100% threads).
// Block (b, sub) owns one sub-region (~32.8K pairs, 32/thread).
// ---------------------------------------------------------------------------
__global__ __launch_bounds__(1024, 8)
void consumer_kernel(const u32*      __restrict__ pairs,
                     const unsigned* __restrict__ counters,
                     float*          __restrict__ partial,
                     unsigned capSub) {
    const int b   = blockIdx.x / kR;
    const int sub = blockIdx.x - b * kR;
    unsigned cnt = counters[(b * kR + sub) * kCtrStride];
    if (cnt > capSub) cnt = capSub;

    __shared__ float acc[kBSpan];
    for (int i = threadIdx.x; i < kBSpan; i += 1024) acc[i] = 0.0f;
    __syncthreads();

    const u32* p = pairs + (size_t)(b * kR + sub) * capSub;
    const unsigned aligned = cnt & ~3u;
    for (unsigned i = 4 * threadIdx.x; i < aligned; i += 4096) {
        u32x4 e = *((const u32x4*)(p + i));
#pragma unroll
        for (int j = 0; j < 4; ++j)
            atomicAdd(&acc[e[j] >> 19], __uint_as_float(e[j] << 13));
    }
    if (threadIdx.x < (cnt - aligned)) {
        u32 e = p[aligned + threadIdx.x];
        atomicAdd(&acc[e >> 19], __uint_as_float(e << 13));
    }
    __syncthreads();

    float* dst = partial + (size_t)(b * kR + sub) * kBSpan;
    for (int k = threadIdx.x; k < kBSpan; k += 1024) dst[k] = acc[k];
}

// ---------------------------------------------------------------------------
// Norm + finalize: block (b, chunk of 1024 dofs); vectorized sum over kR
// planes; done-counter finalize; last thread reduces rho partials.
// acc layout: acc[1]=norm_sum, acc[2]=done counter (uint).
// ---------------------------------------------------------------------------
__global__ void norm_kernel(const float* __restrict__ partial,
                            const float* __restrict__ f,
                            float* __restrict__ acc,
                            const float* __restrict__ rho_part,
                            float* __restrict__ out) {
    const int b  = blockIdx.x >> 3;
    const int i0 = (blockIdx.x & 7) * 1024 + threadIdx.x * 4;
    f32x4 s = {0.0f, 0.0f, 0.0f, 0.0f};
#pragma unroll
    for (int r = 0; r < kR; ++r)
        s += *(const f32x4*)(partial + (size_t)(b * kR + r) * kBSpan + i0);
    f32x4 fv = *(const f32x4*)(f + (size_t)b * kBSpan + i0);
    f32x4 d  = s - fv;
    float a = d[0] * d[0] + d[1] * d[1] + d[2] * d[2] + d[3] * d[3];
    for (int off = 32; off > 0; off >>= 1) a += __shfl_down(a, off, 64);
    __shared__ float partial_s[4];
    const int lane = threadIdx.x & 63;
    const int wid  = threadIdx.x >> 6;
    if (lane == 0) partial_s[wid] = a;
    __syncthreads();
    if (threadIdx.x == 0) {
        atomicAdd(&acc[1],
                  partial_s[0] + partial_s[1] + partial_s[2] + partial_s[3]);
        __threadfence();
        unsigned done = atomicAdd((unsigned*)&acc[2], 1u);
        if (done == gridDim.x - 1) {
            float rs = 0.0f;
            for (int i = 0; i < kScaleBlocks; i += 4) {
                f32x4 rp = *(const f32x4*)(rho_part + i);
                rs += rp[0] + rp[1] + rp[2] + rp[3];
            }
            float ns = __hip_atomic_load(&acc[1], __ATOMIC_RELAXED,
                                         __HIP_MEMORY_SCOPE_AGENT);
            float rho_mean = rs * (1.0f / (float)kNME);
            out[0] = fmaxf(rho_mean - kVolfrac, 0.0f) + sqrtf(ns);
        }
    }
}

// ---------------------------------------------------------------------------
// Fallback path (device atomics) if workspace is too small.
// ---------------------------------------------------------------------------
__global__ void scale1_kernel(const float* __restrict__ W_x,
                              float* __restrict__ scale,
                              float* __restrict__ rho_sum) {
    int i = blockIdx.x * blockDim.x + threadIdx.x;
    float rho = 0.0f;
    if (i < kNME) {
        float x = W_x[i];
        rho = 1.0f / (1.0f + __expf(-x));
        scale[i] = kEmin + rho * rho * rho * (kEmax - kEmin);
    }
    for (int off = 32; off > 0; off >>= 1) rho += __shfl_down(rho, off, 64);
    __shared__ float partial[4];
    const int lane = threadIdx.x & 63;
    const int wid  = threadIdx.x >> 6;
    if (lane == 0) partial[wid] = rho;
    __syncthreads();
    if (threadIdx.x == 0)
        atomicAdd(rho_sum, partial[0] + partial[1] + partial[2] + partial[3]);
}

__global__ void scatter_dev_kernel(const float* __restrict__ K_sep,
                                   const int*   __restrict__ rows,
                                   const int*   __restrict__ cols,
                                   const float* __restrict__ u,
                                   const float* __restrict__ scale,
                                   float* __restrict__ Ku) {
    long long i = (long long)blockIdx.x * blockDim.x + threadIdx.x;
    if (i >= kNNZ) return;
    float s = scale[(int)(i >> 6)];
    atomicAdd(&Ku[rows[i]], K_sep[i] * s * u[cols[i]]);
}

__global__ void norm1_kernel(const float* __restrict__ Ku,
                             const float* __restrict__ f,
                             float* __restrict__ norm_sum) {
    float a = 0.0f;
    for (int i = blockIdx.x * blockDim.x + threadIdx.x; i < kNDOF;
         i += gridDim.x * blockDim.x) {
        float d = Ku[i] - f[i];
        a += d * d;
    }
    for (int off = 32; off > 0; off >>= 1) a += __shfl_down(a, off, 64);
    __shared__ float partial_s[4];
    const int lane = threadIdx.x & 63;
    const int wid  = threadIdx.x >> 6;
    if (lane == 0) partial_s[wid] = a;
    __syncthreads();
    if (threadIdx.x == 0)
        atomicAdd(norm_sum,
                  partial_s[0] + partial_s[1] + partial_s[2] + partial_s[3]);
}

__global__ void finalize_kernel(const float* __restrict__ acc,
                                float* __restrict__ out) {
    if (threadIdx.x == 0 && blockIdx.x == 0) {
        float rho_mean = acc[0] * (1.0f / (float)kNME);
        float vol = fmaxf(rho_mean - kVolfrac, 0.0f);
        out[0] = vol + sqrtf(acc[1]);
    }
}

}  // namespace

extern "C" void kernel_launch(void* const* d_in, const int* in_sizes, int n_in,
                              void* d_out, int out_size, void* d_ws, size_t ws_size,
                              hipStream_t stream) {
    const float* W_x   = (const float*)d_in[0];
    const float* K_sep = (const float*)d_in[1];
    const int*   idx   = (const int*)d_in[2];
    const float* u     = (const float*)d_in[3];
    const float* f     = (const float*)d_in[4];
    const int* rows = idx;
    const int* cols = idx + kNNZ;

    float* ws = (float*)d_ws;
    const size_t avail = ws_size / sizeof(float);

    // R=8 config: capSub mean 32768 + 4096 margin (~22 sigma).
    const unsigned capSub = (unsigned)(kNNZ / (kNB * kR)) + 4096;
    const size_t   ctrF   = (size_t)kNB * kR * kCtrStride;         // 8192
    const size_t   headF  = 16;                                    // acc
    const size_t   rhoF   = kScaleBlocks;                          // 1024
    const size_t   partF  = (size_t)kNB * kR * kBSpan;             // 4.2M
    const size_t   need   = headF + ctrF + rhoF + partF + kNME +
                            (size_t)kNB * kR * capSub;

    if (need > avail) {
        // Fallback: device-atomic scatter (fits in ~3.2 MB).
        float* Ku    = ws;
        float* scale = ws + kNDOF;
        float* acc   = ws + kNDOF + kNME;
        hipMemsetAsync(ws, 0, (size_t)(kNDOF + kNME + 16) * sizeof(float), stream);
        scale1_kernel<<<kNME / 256, 256, 0, stream>>>(W_x, scale, acc);
        scatter_dev_kernel<<<(int)(kNNZ / 256), 256, 0, stream>>>(
            K_sep, rows, cols, u, scale, Ku);
        norm1_kernel<<<2048, 256, 0, stream>>>(Ku, f, acc + 1);
        finalize_kernel<<<1, 64, 0, stream>>>(acc, (float*)d_out);
        return;
    }

    float*    acc      = ws;                          // [16] norm@1, done@2
    unsigned* counters = (unsigned*)(ws + headF);     // [kNB*kR*kCtrStride]
    float*    rho_part = ws + headF + ctrF;           // [kScaleBlocks]
    float*    partial  = rho_part + rhoF;             // [kNB*kR*kBSpan]
    float*    scale    = partial + partF;             // [kNME]
    u32*      pairs    = (u32*)(scale + kNME);        // [kNB*kR*capSub]

    // Node 1: scale + workspace init.
    scale_kernel<<<kScaleBlocks, 256, 0, stream>>>(W_x, scale, acc, counters,
                                                   rho_part);

    // Node 2: producer.
    producer_kernel<<<(int)(kNNZ / kEnt), kPTh, 0, stream>>>(
        K_sep, rows, cols, u, scale, pairs, counters, capSub);

    // Node 3: consumer (512 blocks x 1024 threads).
    consumer_kernel<<<kNB * kR, 1024, 0, stream>>>(
        pairs, counters, partial, capSub);

    // Node 4: norm + finalize.
    norm_kernel<<<kNB * (kBSpan / 1024), 256, 0, stream>>>(
        partial, f, acc, rho_part, (float*)d_out);
}